// Round 2
// baseline (9475.882 us; speedup 1.0000x reference)
//
#include <hip/hip_runtime.h>
#include <hip/hip_bf16.h>

typedef __bf16 bf16;
typedef __attribute__((ext_vector_type(8))) __bf16 bf16x8;
typedef __attribute__((ext_vector_type(4))) __bf16 bf16x4;
typedef __attribute__((ext_vector_type(4))) float  f32x4;

#define DEV __device__ __forceinline__

constexpr int V = 32000, E = 512, H = 512, L = 64, NB = 32, H2 = 1024, T = 64, SOS = 127;
constexpr int GE = 4 * H;        // 2048: encoder gate width
constexpr int NCHUNK = 1000;     // logits partial chunks (one per wave)

// ---- ws layout (bytes) ----
constexpr size_t OFF_GIN    = 0;                                  // f32 [2][T][NB][GE]
constexpr size_t SZ_GIN     = (size_t)2*T*NB*GE*4;
constexpr size_t OFF_ENCOUT = OFF_GIN + SZ_GIN;                   // bf16 [NB][L][H2]
constexpr size_t SZ_ENCOUT  = (size_t)NB*L*H2*2;
constexpr size_t OFF_ENCC   = OFF_ENCOUT + SZ_ENCOUT;             // f32 [2][NB][H]
constexpr size_t SZ_ENCC    = (size_t)2*NB*H*4;
constexpr size_t OFF_ENCH   = OFF_ENCC + SZ_ENCC;                 // bf16 [2 parity][2 dir][NB][H]
constexpr size_t SZ_ENCH    = (size_t)2*2*NB*H*2;
constexpr size_t OFF_DECC   = OFF_ENCH + SZ_ENCH;                 // f32 [NB][H2]
constexpr size_t SZ_DECC    = (size_t)NB*H2*4;
constexpr size_t OFF_DECH   = OFF_DECC + SZ_DECC;                 // bf16 [2 parity][NB][H2]
constexpr size_t SZ_DECH    = (size_t)2*NB*H2*2;
constexpr size_t OFF_CAT2   = OFF_DECH + SZ_DECH;                 // bf16 [NB][2*H2]
constexpr size_t SZ_CAT2    = (size_t)NB*2*H2*2;
constexpr size_t OFF_COMB   = OFF_CAT2 + SZ_CAT2;                 // bf16 [NB][H2]
constexpr size_t SZ_COMB    = (size_t)NB*H2*2;
constexpr size_t OFF_PMAX   = OFF_COMB + SZ_COMB;                 // f32 [NCHUNK][NB]
constexpr size_t SZ_P       = (size_t)NCHUNK*NB*4;
constexpr size_t OFF_PSUM   = OFF_PMAX + SZ_P;
constexpr size_t OFF_PIDX   = OFF_PSUM + SZ_P;
constexpr size_t OFF_LOGZ   = OFF_PIDX + SZ_P;                    // f32 [T][NB]
constexpr size_t SZ_LOGZ    = (size_t)T*NB*4;
// bf16 weight copies (converted from f32 inputs once per call)
constexpr size_t OFF_WEFIH  = OFF_LOGZ + SZ_LOGZ;                 // bf16 [4H][E]
constexpr size_t SZ_WENC    = (size_t)GE*E*2;
constexpr size_t OFF_WEFHH  = OFF_WEFIH + SZ_WENC;                // bf16 [4H][H]
constexpr size_t OFF_WEBIH  = OFF_WEFHH + SZ_WENC;
constexpr size_t OFF_WEBHH  = OFF_WEBIH + SZ_WENC;
constexpr size_t OFF_WCOMB  = OFF_WEBHH + SZ_WENC;                // bf16 [H2][2*H2]
constexpr size_t SZ_WCOMB   = (size_t)H2*2*H2*2;
constexpr size_t OFF_WDIH   = OFF_WCOMB + SZ_WCOMB;               // bf16 [4*H2][H2]
constexpr size_t SZ_WDEC    = (size_t)4*H2*H2*2;
constexpr size_t OFF_WDHH   = OFF_WDIH + SZ_WDEC;
constexpr size_t OFF_WOUT   = OFF_WDHH + SZ_WDEC;                 // bf16 [V][H2]
constexpr size_t SZ_WOUT    = (size_t)V*H2*2;
constexpr size_t OFF_EMB2   = OFF_WOUT + SZ_WOUT;                 // bf16 [T*NB][E], row m=(t<<5)|b
constexpr size_t SZ_EMB2    = (size_t)T*NB*E*2;

DEV f32x4 mfma16(bf16x8 a, bf16x8 b, f32x4 c) {
  return __builtin_amdgcn_mfma_f32_16x16x32_bf16(a, b, c, 0, 0, 0);
}
DEV float sigm(float x) { return 1.f / (1.f + __expf(-x)); }
DEV bf16x8 ld8(const bf16* p) { return *(const bf16x8*)p; }

// --------------------------------------------------- f32 -> bf16 converter
__global__ __launch_bounds__(256) void k_convert(const float* __restrict__ src,
                                                 bf16* __restrict__ dst, long n8) {
  long i = (long)blockIdx.x * 256 + threadIdx.x;
  long stride = (long)gridDim.x * 256;
  for (long g = i; g < n8; g += stride) {
    long o = g * 8;
    float4 a = *(const float4*)(src + o);
    float4 b = *(const float4*)(src + o + 4);
    bf16x8 v;
    v[0]=(bf16)a.x; v[1]=(bf16)a.y; v[2]=(bf16)a.z; v[3]=(bf16)a.w;
    v[4]=(bf16)b.x; v[5]=(bf16)b.y; v[6]=(bf16)b.z; v[7]=(bf16)b.w;
    *(bf16x8*)(dst + o) = v;
  }
}

// ------------------------------------- gather+convert encoder embeddings
// emb2[m][k] = (bf16) enc_embed[x[b][t]][k],  m = (t<<5)|b
__global__ __launch_bounds__(256) void k_gather_emb(const int* __restrict__ x,
                                                    const float* __restrict__ embed,
                                                    bf16* __restrict__ emb2) {
  int gid = blockIdx.x * 256 + threadIdx.x;     // grid 512 -> 131072 threads
  int m = gid >> 6, k8 = (gid & 63) * 8;
  int b = m & 31, t = m >> 5;
  int tok = x[b * L + t];
  const float* src = embed + (long)tok * E + k8;
  float4 a = *(const float4*)src;
  float4 c = *(const float4*)(src + 4);
  bf16x8 v;
  v[0]=(bf16)a.x; v[1]=(bf16)a.y; v[2]=(bf16)a.z; v[3]=(bf16)a.w;
  v[4]=(bf16)c.x; v[5]=(bf16)c.y; v[6]=(bf16)c.z; v[7]=(bf16)c.w;
  *(bf16x8*)(emb2 + (long)m * E + k8) = v;
}

// ---------------------------------------------------------------- init states
__global__ __launch_bounds__(256) void k_init(float* encc, bf16* ench, float* decc, bf16* dech) {
  int i = blockIdx.x * 256 + threadIdx.x;          // grid 256 -> 65536 threads
  if (i < 2*NB*H) { encc[i] = 0.f; }
  if (i < NB*H2)  { decc[i] = 0.f; }
  ench[i] = (bf16)0.f;
  dech[i] = (bf16)0.f;
}

// ------------------------------------------- encoder input gates (both dirs)
// gin[dir][t][b][n] = emb2 @ Wih.T + bias   (M=2048 rows(m), N=2048 gates, K=512)
__global__ __launch_bounds__(256) void k_enc_ingemm(
    const bf16* __restrict__ emb2,
    const bf16* __restrict__ fWih, const float* __restrict__ fB,
    const bf16* __restrict__ bWih, const float* __restrict__ bB,
    float* __restrict__ gin)
{
  int wid  = blockIdx.x * 4 + (threadIdx.x >> 6);
  int lane = threadIdx.x & 63;
  int dir  = wid >> 11;
  int w2   = wid & 2047;
  int m0   = (w2 >> 5) * 32;
  int n0   = (w2 & 31) * 64;
  const bf16*  Wih  = dir ? bWih : fWih;
  const float* Bias = dir ? bB : fB;
  int col = lane & 15, kq = lane >> 4, r4 = kq * 4;

  const bf16* arow[4];
#pragma unroll
  for (int nt = 0; nt < 4; ++nt) arow[nt] = Wih + (long)(n0 + nt*16 + col)*E + kq*8;
  const bf16* brow[2];
#pragma unroll
  for (int mt = 0; mt < 2; ++mt) brow[mt] = emb2 + (long)(m0 + mt*16 + col)*E + kq*8;

  f32x4 acc[2][4] = {};
  for (int kk = 0; kk < E/32; ++kk) {
    bf16x8 a[4], bv[2];
#pragma unroll
    for (int nt = 0; nt < 4; ++nt) a[nt] = ld8(arow[nt] + kk*32);
#pragma unroll
    for (int mt = 0; mt < 2; ++mt) bv[mt] = ld8(brow[mt] + kk*32);
#pragma unroll
    for (int mt = 0; mt < 2; ++mt)
#pragma unroll
      for (int nt = 0; nt < 4; ++nt)
        acc[mt][nt] = mfma16(a[nt], bv[mt], acc[mt][nt]);
  }
#pragma unroll
  for (int mt = 0; mt < 2; ++mt) {
    int m = m0 + mt*16 + col;
    int b = m & 31, t = m >> 5;
    float* gp = gin + ((long)(dir*T + t)*NB + b)*GE;
#pragma unroll
    for (int nt = 0; nt < 4; ++nt) {
      int nb = n0 + nt*16 + r4;
      f32x4 v = acc[mt][nt];
      float4 o;
      o.x = v[0] + Bias[nb+0];
      o.y = v[1] + Bias[nb+1];
      o.z = v[2] + Bias[nb+2];
      o.w = v[3] + Bias[nb+3];
      *(float4*)(gp + nb) = o;
    }
  }
}

// ---------------------------------------------- encoder recurrent step (t)
__global__ __launch_bounds__(256) void k_enc_step(
    const bf16* __restrict__ fWhh, const bf16* __restrict__ bWhh,
    const float* __restrict__ gin, float* __restrict__ encc,
    const bf16* __restrict__ hin, bf16* __restrict__ hout,
    bf16* __restrict__ encout, int t)
{
  __shared__ float lds[4][16][32];
  int tid = threadIdx.x;
  int w = tid >> 6, lane = tid & 63;
  int dir = blockIdx.x >> 5;
  int j0  = (blockIdx.x & 31) * 16;
  const bf16* Whh   = dir ? bWhh : fWhh;
  const bf16* hbase = hin + dir*(NB*H);
  int col = lane & 15, kq = lane >> 4, r4 = kq*4;
  const bf16* arow = Whh + (long)(w*H + j0 + col)*H + kq*8;
  const bf16* b0 = hbase + col*H + kq*8;
  const bf16* b1 = hbase + (16+col)*H + kq*8;
  f32x4 a0 = {}, a1 = {};
  for (int kk = 0; kk < H/32; ++kk) {
    bf16x8 a = ld8(arow + kk*32);
    a0 = mfma16(a, ld8(b0 + kk*32), a0);
    a1 = mfma16(a, ld8(b1 + kk*32), a1);
  }
#pragma unroll
  for (int r = 0; r < 4; ++r) { lds[w][r4+r][col] = a0[r]; lds[w][r4+r][16+col] = a1[r]; }
  __syncthreads();
  const float* gp = gin + (long)(dir*T + t)*NB*GE;
  for (int idx = tid; idx < 512; idx += 256) {
    int jj = idx >> 5, b = idx & 31;
    int j = j0 + jj;
    const float* g4 = gp + (long)b*GE;
    float ig = lds[0][jj][b] + g4[0*H + j];
    float fg = lds[1][jj][b] + g4[1*H + j];
    float gg = lds[2][jj][b] + g4[2*H + j];
    float og = lds[3][jj][b] + g4[3*H + j];
    float i_ = sigm(ig), f_ = sigm(fg), o_ = sigm(og), g_ = tanhf(gg);
    int ci = (dir*NB + b)*H + j;
    float c2 = f_*encc[ci] + i_*g_;
    encc[ci] = c2;
    float h = o_*tanhf(c2);
    hout[dir*(NB*H) + b*H + j] = (bf16)h;
    encout[((long)b*L + t)*H2 + dir*H + j] = (bf16)h;
  }
}

// -------------------- decoder K1: argmax-reduce + embed + attention + ctx
__global__ __launch_bounds__(256) void k_dec_attn(
    const float* __restrict__ dec_embed, const float* __restrict__ attn_W,
    const float* __restrict__ attn_b, const bf16* __restrict__ encout,
    const bf16* __restrict__ hin,
    const float* __restrict__ pmax, const float* __restrict__ psum,
    const int* __restrict__ pidx,
    float* __restrict__ logz, bf16* __restrict__ cat2, int t)
{
  __shared__ float red_m[256], red_s[256];
  __shared__ int   red_i[256];
  __shared__ float catF[2*H2];
  __shared__ float aw[64];
  __shared__ int stok;
  int tid = threadIdx.x, b = blockIdx.x;

  if (t > 0) {                       // finish step t-1: logZ + argmax token
    float m = -1e30f, s = 0.f; int id = 0;
    for (int c = tid; c < NCHUNK; c += 256) {
      float cm = pmax[c*32 + b]; int ci = pidx[c*32 + b];
      s += psum[c*32 + b];
      if (cm > m) { m = cm; id = ci; }
      else if (cm == m && ci < id) { id = ci; }
    }
    red_m[tid] = m; red_s[tid] = s; red_i[tid] = id;
    __syncthreads();
    for (int off = 128; off; off >>= 1) {
      if (tid < off) {
        float om = red_m[tid+off]; int oi = red_i[tid+off];
        red_s[tid] += red_s[tid+off];
        if (om > red_m[tid] || (om == red_m[tid] && oi < red_i[tid])) { red_m[tid]=om; red_i[tid]=oi; }
      }
      __syncthreads();
    }
    if (tid == 0) { logz[(t-1)*32 + b] = logf(red_s[0]); stok = red_i[0]; }
  } else {
    if (tid == 0) stok = SOS;
  }
  __syncthreads();
  int tok = stok;

  // phase 1: catF = [e, h] (f32 in LDS); e -> cat2 ws as bf16
  const float* erow = dec_embed + (long)tok*H2;
  bf16* c2row = cat2 + (long)b*(2*H2);
  if (tid < 128) {
    int o = tid*8;
    float4 a = *(const float4*)(erow + o);
    float4 c = *(const float4*)(erow + o + 4);
    catF[o+0]=a.x; catF[o+1]=a.y; catF[o+2]=a.z; catF[o+3]=a.w;
    catF[o+4]=c.x; catF[o+5]=c.y; catF[o+6]=c.z; catF[o+7]=c.w;
    bf16x8 v;
    v[0]=(bf16)a.x; v[1]=(bf16)a.y; v[2]=(bf16)a.z; v[3]=(bf16)a.w;
    v[4]=(bf16)c.x; v[5]=(bf16)c.y; v[6]=(bf16)c.z; v[7]=(bf16)c.w;
    *(bf16x8*)(c2row + o) = v;
  } else {
    int o = (tid - 128)*8;
    bf16x8 hv = ld8(hin + (long)b*H2 + o);
#pragma unroll
    for (int e = 0; e < 8; ++e) catF[H2 + o + e] = (float)hv[e];
  }
  __syncthreads();

  // phase 2: scores[l] = catF . attn_W[l] + attn_b[l]   (4 threads per l)
  {
    int l = tid >> 2, q = tid & 3;
    const float* wrow = attn_W + (long)l*(2*H2) + q*512;
    const float* crow = catF + q*512;
    float sacc = 0.f;
    for (int k = 0; k < 512; k += 4) {
      float4 w = *(const float4*)(wrow + k);
      sacc += w.x*crow[k] + w.y*crow[k+1] + w.z*crow[k+2] + w.w*crow[k+3];
    }
    sacc += __shfl_xor(sacc, 1);
    sacc += __shfl_xor(sacc, 2);
    if (q == 0) aw[l] = sacc + attn_b[l];
  }
  __syncthreads();

  // phase 3: softmax over L=64 (wave 0)
  if (tid < 64) {
    float v = aw[tid];
    float m = v;
#pragma unroll
    for (int off = 1; off < 64; off <<= 1) m = fmaxf(m, __shfl_xor(m, off));
    float p = __expf(v - m);
    float s = p;
#pragma unroll
    for (int off = 1; off < 64; off <<= 1) s += __shfl_xor(s, off);
    aw[tid] = p / s;
  }
  __syncthreads();

  // phase 4: ctx[j] = sum_l aw[l] * enc_outs[b][l][j]  -> cat2[b][H2+j] bf16
  {
    const bf16* eo = encout + (long)b*L*H2;
    int j = tid * 4;
    float4 acc = {0.f, 0.f, 0.f, 0.f};
    for (int l = 0; l < L; ++l) {
      float a = aw[l];
      bf16x4 v = *(const bf16x4*)(eo + (long)l*H2 + j);
      acc.x += a*(float)v[0]; acc.y += a*(float)v[1];
      acc.z += a*(float)v[2]; acc.w += a*(float)v[3];
    }
    bf16x4 o;
    o[0] = (bf16)acc.x; o[1] = (bf16)acc.y; o[2] = (bf16)acc.z; o[3] = (bf16)acc.w;
    *(bf16x4*)(c2row + H2 + j) = o;
  }
}

// -------------------------- decoder K1b: comb = relu(cat2 @ comb_W.T + b)
__global__ __launch_bounds__(256) void k_dec_comb(
    const bf16* __restrict__ comb_W, const float* __restrict__ comb_b,
    const bf16* __restrict__ cat2, bf16* __restrict__ comb)
{
  int wid = blockIdx.x * 4 + (threadIdx.x >> 6);  // 0..15
  int lane = threadIdx.x & 63;
  int col = lane & 15, kq = lane >> 4, r4 = kq*4;
  int n0 = wid * 64;
  const bf16* arow[4];
#pragma unroll
  for (int nt = 0; nt < 4; ++nt) arow[nt] = comb_W + (long)(n0 + nt*16 + col)*(2*H2) + kq*8;
  const bf16* b0 = cat2 + (long)col*(2*H2) + kq*8;
  const bf16* b1 = cat2 + (long)(16+col)*(2*H2) + kq*8;
  f32x4 acc[4][2] = {};
  for (int kk = 0; kk < 64; ++kk) {
    bf16x8 bv0 = ld8(b0 + kk*32);
    bf16x8 bv1 = ld8(b1 + kk*32);
#pragma unroll
    for (int nt = 0; nt < 4; ++nt) {
      bf16x8 a = ld8(arow[nt] + kk*32);
      acc[nt][0] = mfma16(a, bv0, acc[nt][0]);
      acc[nt][1] = mfma16(a, bv1, acc[nt][1]);
    }
  }
#pragma unroll
  for (int nt = 0; nt < 4; ++nt) {
    int nb = n0 + nt*16 + r4;
#pragma unroll
    for (int bt = 0; bt < 2; ++bt) {
      int b = bt*16 + col;
      f32x4 v = acc[nt][bt];
      bf16x4 o;
#pragma unroll
      for (int r = 0; r < 4; ++r) {
        float xv = v[r] + comb_b[nb + r];
        o[r] = (bf16)fmaxf(xv, 0.f);
      }
      *(bf16x4*)(comb + (long)b*H2 + nb) = o;
    }
  }
}

// ---------------- decoder K2: gates = comb@dWih.T + h@dWhh.T + b; LSTM cell
__global__ __launch_bounds__(256) void k_dec_cell(
    const bf16* __restrict__ dWih, const bf16* __restrict__ dWhh,
    const float* __restrict__ db, const bf16* __restrict__ comb,
    const bf16* __restrict__ hin, float* __restrict__ decc,
    bf16* __restrict__ hout)
{
  __shared__ float lds[4][16][32];
  int tid = threadIdx.x, w = tid >> 6, lane = tid & 63;
  int col = lane & 15, kq = lane >> 4, r4 = kq*4;
  int j0 = blockIdx.x * 16;
  int n = w*H2 + j0 + col;
  f32x4 a0 = {}, a1 = {};
  {
    const bf16* arow = dWih + (long)n*H2 + kq*8;
    const bf16* b0 = comb + (long)col*H2 + kq*8;
    const bf16* b1 = comb + (long)(16+col)*H2 + kq*8;
    for (int kk = 0; kk < 32; ++kk) {
      bf16x8 a = ld8(arow + kk*32);
      a0 = mfma16(a, ld8(b0 + kk*32), a0);
      a1 = mfma16(a, ld8(b1 + kk*32), a1);
    }
  }
  {
    const bf16* arow = dWhh + (long)n*H2 + kq*8;
    const bf16* b0 = hin + (long)col*H2 + kq*8;
    const bf16* b1 = hin + (long)(16+col)*H2 + kq*8;
    for (int kk = 0; kk < 32; ++kk) {
      bf16x8 a = ld8(arow + kk*32);
      a0 = mfma16(a, ld8(b0 + kk*32), a0);
      a1 = mfma16(a, ld8(b1 + kk*32), a1);
    }
  }
#pragma unroll
  for (int r = 0; r < 4; ++r) {
    float bias = db[w*H2 + j0 + r4 + r];
    lds[w][r4+r][col] = a0[r] + bias;
    lds[w][r4+r][16+col] = a1[r] + bias;
  }
  __syncthreads();
  for (int idx = tid; idx < 512; idx += 256) {
    int jj = idx >> 5, b = idx & 31;
    int j = j0 + jj;
    float i_ = sigm(lds[0][jj][b]);
    float f_ = sigm(lds[1][jj][b]);
    float g_ = tanhf(lds[2][jj][b]);
    float o_ = sigm(lds[3][jj][b]);
    float c2 = f_*decc[b*H2 + j] + i_*g_;
    decc[b*H2 + j] = c2;
    hout[b*H2 + j] = (bf16)(o_*tanhf(c2));
  }
}

// ------------- decoder K3: logits (f32) -> d_out raw, + per-wave partials
__global__ __launch_bounds__(256) void k_dec_logits(
    const bf16* __restrict__ outW, const float* __restrict__ outb,
    const bf16* __restrict__ hvec, float* __restrict__ out,
    float* __restrict__ pmax, float* __restrict__ psum, int* __restrict__ pidx,
    int t)
{
  int wid = blockIdx.x * 4 + (threadIdx.x >> 6);  // 0..999
  int lane = threadIdx.x & 63;
  int col = lane & 15, kq = lane >> 4, r4 = kq*4;
  int n0 = wid * 32;
  const bf16* arow[2];
#pragma unroll
  for (int nt = 0; nt < 2; ++nt) arow[nt] = outW + (long)(n0 + nt*16 + col)*H2 + kq*8;
  const bf16* b0 = hvec + (long)col*H2 + kq*8;
  const bf16* b1 = hvec + (long)(16+col)*H2 + kq*8;
  f32x4 acc[2][2] = {};
  for (int kk = 0; kk < 32; ++kk) {
    bf16x8 bv0 = ld8(b0 + kk*32);
    bf16x8 bv1 = ld8(b1 + kk*32);
#pragma unroll
    for (int nt = 0; nt < 2; ++nt) {
      bf16x8 a = ld8(arow[nt] + kk*32);
      acc[nt][0] = mfma16(a, bv0, acc[nt][0]);
      acc[nt][1] = mfma16(a, bv1, acc[nt][1]);
    }
  }
  float m[2] = {-1e30f, -1e30f};
  float s[2] = {0.f, 0.f};
  int  id[2] = {0, 0};
#pragma unroll
  for (int bt = 0; bt < 2; ++bt) {
    int b = bt*16 + col;
    float* orow = out + ((long)b*T + t)*V;
#pragma unroll
    for (int nt = 0; nt < 2; ++nt) {
      int nb = n0 + nt*16 + r4;
      f32x4 v = acc[nt][bt];
      float4 o;
      float xs[4];
#pragma unroll
      for (int r = 0; r < 4; ++r) {
        float xv = v[r] + outb[nb + r];
        xs[r] = xv;
        s[bt] += __expf(xv);
        if (xv > m[bt]) { m[bt] = xv; id[bt] = nb + r; }
      }
      o.x = xs[0]; o.y = xs[1]; o.z = xs[2]; o.w = xs[3];
      *(float4*)(orow + nb) = o;
    }
  }
#pragma unroll
  for (int off = 16; off <= 32; off <<= 1) {
#pragma unroll
    for (int bt = 0; bt < 2; ++bt) {
      float om = __shfl_xor(m[bt], off);
      float os = __shfl_xor(s[bt], off);
      int   oi = __shfl_xor(id[bt], off);
      s[bt] += os;
      if (om > m[bt] || (om == m[bt] && oi < id[bt])) { m[bt] = om; id[bt] = oi; }
    }
  }
  if (lane < 16) {
#pragma unroll
    for (int bt = 0; bt < 2; ++bt) {
      int b = bt*16 + lane;
      pmax[wid*32 + b] = m[bt];
      psum[wid*32 + b] = s[bt];
      pidx[wid*32 + b] = id[bt];
    }
  }
}

// ------------------------------------------------ logZ for the last step
__global__ __launch_bounds__(256) void k_reduce_last(const float* __restrict__ psum,
                                                     float* __restrict__ logz)
{
  __shared__ float red_s[256];
  int tid = threadIdx.x, b = blockIdx.x;
  float s = 0.f;
  for (int c = tid; c < NCHUNK; c += 256) s += psum[c*32 + b];
  red_s[tid] = s;
  __syncthreads();
  for (int off = 128; off; off >>= 1) { if (tid < off) red_s[tid] += red_s[tid+off]; __syncthreads(); }
  if (tid == 0) logz[63*32 + b] = logf(red_s[0]);
}

// ------------------------- final: out[b][t][v] = raw_logit - logZ[t][b]
__global__ __launch_bounds__(256) void k_fixup(float* __restrict__ out,
                                               const float* __restrict__ logz)
{
  long i = (long)blockIdx.x * 256 + threadIdx.x;
  long stride = (long)gridDim.x * 256;
  long total = (long)NB * T * V / 4;
  for (long g = i; g < total; g += stride) {
    long flat = g * 4;
    long bt = flat / V;                 // = b*T + t
    int tt = (int)(bt & 63), b = (int)(bt >> 6);
    float lz = logz[tt*32 + b];
    float4 v = *(const float4*)(out + flat);
    v.x -= lz; v.y -= lz; v.z -= lz; v.w -= lz;
    *(float4*)(out + flat) = v;
  }
}

extern "C" void kernel_launch(void* const* d_in, const int* in_sizes, int n_in,
                              void* d_out, int out_size, void* d_ws, size_t ws_size,
                              hipStream_t stream)
{
  const int*   x         = (const int*)  d_in[0];
  const float* enc_embed = (const float*)d_in[1];
  const float* ef_Wih    = (const float*)d_in[2];
  const float* ef_Whh    = (const float*)d_in[3];
  const float* ef_b      = (const float*)d_in[4];
  const float* eb_Wih    = (const float*)d_in[5];
  const float* eb_Whh    = (const float*)d_in[6];
  const float* eb_b      = (const float*)d_in[7];
  const float* dec_embed = (const float*)d_in[8];
  const float* attn_W    = (const float*)d_in[9];
  const float* attn_b    = (const float*)d_in[10];
  const float* comb_W    = (const float*)d_in[11];
  const float* comb_b    = (const float*)d_in[12];
  const float* d_Wih     = (const float*)d_in[13];
  const float* d_Whh     = (const float*)d_in[14];
  const float* d_b       = (const float*)d_in[15];
  const float* out_W     = (const float*)d_in[16];
  const float* out_b     = (const float*)d_in[17];
  float* out = (float*)d_out;
  char* ws = (char*)d_ws;

  float* gin    = (float*)(ws + OFF_GIN);
  bf16*  encout = (bf16*) (ws + OFF_ENCOUT);
  float* encc   = (float*)(ws + OFF_ENCC);
  bf16*  ench   = (bf16*) (ws + OFF_ENCH);
  float* decc   = (float*)(ws + OFF_DECC);
  bf16*  dech   = (bf16*) (ws + OFF_DECH);
  bf16*  cat2   = (bf16*) (ws + OFF_CAT2);
  bf16*  comb   = (bf16*) (ws + OFF_COMB);
  float* pmax   = (float*)(ws + OFF_PMAX);
  float* psum   = (float*)(ws + OFF_PSUM);
  int*   pidx   = (int*)  (ws + OFF_PIDX);
  float* logz   = (float*)(ws + OFF_LOGZ);
  bf16*  wefih  = (bf16*) (ws + OFF_WEFIH);
  bf16*  wefhh  = (bf16*) (ws + OFF_WEFHH);
  bf16*  webih  = (bf16*) (ws + OFF_WEBIH);
  bf16*  webhh  = (bf16*) (ws + OFF_WEBHH);
  bf16*  wcomb  = (bf16*) (ws + OFF_WCOMB);
  bf16*  wdih   = (bf16*) (ws + OFF_WDIH);
  bf16*  wdhh   = (bf16*) (ws + OFF_WDHH);
  bf16*  wout   = (bf16*) (ws + OFF_WOUT);
  bf16*  emb2   = (bf16*) (ws + OFF_EMB2);

  // one-time f32 -> bf16 weight conversion (per call; deterministic)
  auto conv = [&](const float* s, bf16* d, long n) {
    long n8 = n / 8;
    int grid = (int)((n8 + 255) / 256);
    if (grid > 2048) grid = 2048;
    hipLaunchKernelGGL(k_convert, dim3(grid), dim3(256), 0, stream, s, d, n8);
  };
  conv(ef_Wih, wefih, (long)GE*E);
  conv(ef_Whh, wefhh, (long)GE*H);
  conv(eb_Wih, webih, (long)GE*E);
  conv(eb_Whh, webhh, (long)GE*H);
  conv(comb_W, wcomb, (long)H2*2*H2);
  conv(d_Wih,  wdih,  (long)4*H2*H2);
  conv(d_Whh,  wdhh,  (long)4*H2*H2);
  conv(out_W,  wout,  (long)V*H2);
  hipLaunchKernelGGL(k_gather_emb, dim3(512), dim3(256), 0, stream, x, enc_embed, emb2);

  hipLaunchKernelGGL(k_init, dim3(256), dim3(256), 0, stream, encc, ench, decc, dech);
  hipLaunchKernelGGL(k_enc_ingemm, dim3(1024), dim3(256), 0, stream,
                     emb2, wefih, ef_b, webih, eb_b, gin);
  for (int t = 0; t < T; ++t) {
    const bf16* hi = ench + (t & 1) * (2*NB*H);
    bf16*       ho = ench + ((t & 1) ^ 1) * (2*NB*H);
    hipLaunchKernelGGL(k_enc_step, dim3(64), dim3(256), 0, stream,
                       wefhh, webhh, gin, encc, hi, ho, encout, t);
  }
  for (int t = 0; t < T; ++t) {
    const bf16* hi = dech + (t & 1) * (NB*H2);
    bf16*       ho = dech + ((t & 1) ^ 1) * (NB*H2);
    hipLaunchKernelGGL(k_dec_attn, dim3(32), dim3(256), 0, stream,
                       dec_embed, attn_W, attn_b, encout, hi, pmax, psum, pidx, logz, cat2, t);
    hipLaunchKernelGGL(k_dec_comb, dim3(4), dim3(256), 0, stream, wcomb, comb_b, cat2, comb);
    hipLaunchKernelGGL(k_dec_cell, dim3(64), dim3(256), 0, stream,
                       wdih, wdhh, d_b, comb, hi, decc, ho);
    hipLaunchKernelGGL(k_dec_logits, dim3(250), dim3(256), 0, stream,
                       wout, out_b, ho, out, pmax, psum, pidx, t);
  }
  hipLaunchKernelGGL(k_reduce_last, dim3(32), dim3(256), 0, stream, psum, logz);
  hipLaunchKernelGGL(k_fixup, dim3(2048), dim3(256), 0, stream, out, logz);
}

// Round 3
// 6813.583 us; speedup vs baseline: 1.3907x; 1.3907x over previous
//
#include <hip/hip_runtime.h>
#include <hip/hip_bf16.h>

typedef __bf16 bf16;
typedef __attribute__((ext_vector_type(8))) __bf16 bf16x8;
typedef __attribute__((ext_vector_type(4))) __bf16 bf16x4;
typedef __attribute__((ext_vector_type(4))) float  f32x4;

#define DEV __device__ __forceinline__

constexpr int V = 32000, E = 512, H = 512, L = 64, NB = 32, H2 = 1024, T = 64, SOS = 127;
constexpr int GE = 4 * H;        // 2048: encoder gate width
constexpr int NCHUNK = 2000;     // logits partial chunks (one per wave, 16 rows each)

// ---- ws layout (bytes) ----
constexpr size_t OFF_GIN    = 0;                                  // f32 [2][T][NB][GE]
constexpr size_t SZ_GIN     = (size_t)2*T*NB*GE*4;
constexpr size_t OFF_ENCOUT = OFF_GIN + SZ_GIN;                   // bf16 [NB][L][H2]
constexpr size_t SZ_ENCOUT  = (size_t)NB*L*H2*2;
constexpr size_t OFF_ENCC   = OFF_ENCOUT + SZ_ENCOUT;             // f32 [2][NB][H]
constexpr size_t SZ_ENCC    = (size_t)2*NB*H*4;
constexpr size_t OFF_ENCH   = OFF_ENCC + SZ_ENCC;                 // bf16 [2 parity][2 dir][NB][H]
constexpr size_t SZ_ENCH    = (size_t)2*2*NB*H*2;
constexpr size_t OFF_DECC   = OFF_ENCH + SZ_ENCH;                 // f32 [NB][H2]
constexpr size_t SZ_DECC    = (size_t)NB*H2*4;
constexpr size_t OFF_DECH   = OFF_DECC + SZ_DECC;                 // bf16 [2 parity][NB][H2]
constexpr size_t SZ_DECH    = (size_t)2*NB*H2*2;
constexpr size_t OFF_CAT2   = OFF_DECH + SZ_DECH;                 // bf16 [NB][2*H2]
constexpr size_t SZ_CAT2    = (size_t)NB*2*H2*2;
constexpr size_t OFF_COMB   = OFF_CAT2 + SZ_CAT2;                 // bf16 [NB][H2]
constexpr size_t SZ_COMB    = (size_t)NB*H2*2;
constexpr size_t OFF_HH     = OFF_COMB + SZ_COMB;                 // f32 [4*H2][NB]  (Whh@h partials)
constexpr size_t SZ_HH      = (size_t)4*H2*NB*4;
constexpr size_t OFF_PMAX   = OFF_HH + SZ_HH;                     // f32 [NCHUNK][NB]
constexpr size_t SZ_P       = (size_t)NCHUNK*NB*4;
constexpr size_t OFF_PSUM   = OFF_PMAX + SZ_P;
constexpr size_t OFF_PIDX   = OFF_PSUM + SZ_P;
constexpr size_t OFF_LOGZ   = OFF_PIDX + SZ_P;                    // f32 [T][NB]
constexpr size_t SZ_LOGZ    = (size_t)T*NB*4;
// bf16 weight copies (converted from f32 inputs once per call)
constexpr size_t OFF_WEFIH  = OFF_LOGZ + SZ_LOGZ;                 // bf16 [4H][E]
constexpr size_t SZ_WENC    = (size_t)GE*E*2;
constexpr size_t OFF_WEFHH  = OFF_WEFIH + SZ_WENC;                // bf16 [4H][H]
constexpr size_t OFF_WEBIH  = OFF_WEFHH + SZ_WENC;
constexpr size_t OFF_WEBHH  = OFF_WEBIH + SZ_WENC;
constexpr size_t OFF_WCOMB  = OFF_WEBHH + SZ_WENC;                // bf16 [H2][2*H2]
constexpr size_t SZ_WCOMB   = (size_t)H2*2*H2*2;
constexpr size_t OFF_WDIH   = OFF_WCOMB + SZ_WCOMB;               // bf16 [4*H2][H2]
constexpr size_t SZ_WDEC    = (size_t)4*H2*H2*2;
constexpr size_t OFF_WDHH   = OFF_WDIH + SZ_WDEC;
constexpr size_t OFF_WOUT   = OFF_WDHH + SZ_WDEC;                 // bf16 [V][H2]
constexpr size_t SZ_WOUT    = (size_t)V*H2*2;
constexpr size_t OFF_WATTN  = OFF_WOUT + SZ_WOUT;                 // bf16 [L][2*H2]
constexpr size_t SZ_WATTN   = (size_t)L*2*H2*2;
constexpr size_t OFF_EMB2   = OFF_WATTN + SZ_WATTN;               // bf16 [T*NB][E], row m=(t<<5)|b
constexpr size_t SZ_EMB2    = (size_t)T*NB*E*2;

DEV f32x4 mfma16(bf16x8 a, bf16x8 b, f32x4 c) {
  return __builtin_amdgcn_mfma_f32_16x16x32_bf16(a, b, c, 0, 0, 0);
}
DEV float sigm(float x) { return 1.f / (1.f + __expf(-x)); }
DEV bf16x8 ld8(const bf16* p) { return *(const bf16x8*)p; }

// --------------------------------------- one-shot f32 -> bf16 conversions
struct ConvJobs { const float* src[9]; bf16* dst[9]; long n8[9]; };

__global__ __launch_bounds__(256) void k_convert_all(ConvJobs J) {
  long i0 = (long)blockIdx.x * 256 + threadIdx.x;
  long stride = (long)gridDim.x * 256;
  for (int j = 0; j < 9; ++j) {
    const float* __restrict__ src = J.src[j];
    bf16* __restrict__ dst = J.dst[j];
    long n8 = J.n8[j];
    for (long g = i0; g < n8; g += stride) {
      long o = g * 8;
      float4 a = *(const float4*)(src + o);
      float4 b = *(const float4*)(src + o + 4);
      bf16x8 v;
      v[0]=(bf16)a.x; v[1]=(bf16)a.y; v[2]=(bf16)a.z; v[3]=(bf16)a.w;
      v[4]=(bf16)b.x; v[5]=(bf16)b.y; v[6]=(bf16)b.z; v[7]=(bf16)b.w;
      *(bf16x8*)(dst + o) = v;
    }
  }
}

// ------------------------------------- gather+convert encoder embeddings
__global__ __launch_bounds__(256) void k_gather_emb(const int* __restrict__ x,
                                                    const float* __restrict__ embed,
                                                    bf16* __restrict__ emb2) {
  int gid = blockIdx.x * 256 + threadIdx.x;     // grid 512 -> 131072 threads
  int m = gid >> 6, k8 = (gid & 63) * 8;
  int b = m & 31, t = m >> 5;
  int tok = x[b * L + t];
  const float* src = embed + (long)tok * E + k8;
  float4 a = *(const float4*)src;
  float4 c = *(const float4*)(src + 4);
  bf16x8 v;
  v[0]=(bf16)a.x; v[1]=(bf16)a.y; v[2]=(bf16)a.z; v[3]=(bf16)a.w;
  v[4]=(bf16)c.x; v[5]=(bf16)c.y; v[6]=(bf16)c.z; v[7]=(bf16)c.w;
  *(bf16x8*)(emb2 + (long)m * E + k8) = v;
}

// ---------------------------------------------------------------- init states
__global__ __launch_bounds__(256) void k_init(float* encc, bf16* ench, float* decc,
                                              bf16* dech, float* hh) {
  int i = blockIdx.x * 256 + threadIdx.x;          // grid 512 -> 131072 threads
  hh[i] = 0.f;                                     // 131072
  if (i < 65536) { ench[i] = (bf16)0.f; dech[i] = (bf16)0.f; }
  if (i < 32768) { encc[i] = 0.f; decc[i] = 0.f; }
}

// ------------------------------------------- encoder input gates (both dirs)
__global__ __launch_bounds__(256) void k_enc_ingemm(
    const bf16* __restrict__ emb2,
    const bf16* __restrict__ fWih, const float* __restrict__ fB,
    const bf16* __restrict__ bWih, const float* __restrict__ bB,
    float* __restrict__ gin)
{
  int wid  = blockIdx.x * 4 + (threadIdx.x >> 6);
  int lane = threadIdx.x & 63;
  int dir  = wid >> 11;
  int w2   = wid & 2047;
  int m0   = (w2 >> 5) * 32;
  int n0   = (w2 & 31) * 64;
  const bf16*  Wih  = dir ? bWih : fWih;
  const float* Bias = dir ? bB : fB;
  int col = lane & 15, kq = lane >> 4, r4 = kq * 4;

  const bf16* arow[4];
#pragma unroll
  for (int nt = 0; nt < 4; ++nt) arow[nt] = Wih + (long)(n0 + nt*16 + col)*E + kq*8;
  const bf16* brow[2];
#pragma unroll
  for (int mt = 0; mt < 2; ++mt) brow[mt] = emb2 + (long)(m0 + mt*16 + col)*E + kq*8;

  f32x4 acc[2][4] = {};
  for (int kk = 0; kk < E/32; ++kk) {
    bf16x8 a[4], bv[2];
#pragma unroll
    for (int nt = 0; nt < 4; ++nt) a[nt] = ld8(arow[nt] + kk*32);
#pragma unroll
    for (int mt = 0; mt < 2; ++mt) bv[mt] = ld8(brow[mt] + kk*32);
#pragma unroll
    for (int mt = 0; mt < 2; ++mt)
#pragma unroll
      for (int nt = 0; nt < 4; ++nt)
        acc[mt][nt] = mfma16(a[nt], bv[mt], acc[mt][nt]);
  }
#pragma unroll
  for (int mt = 0; mt < 2; ++mt) {
    int m = m0 + mt*16 + col;
    int b = m & 31, t = m >> 5;
    float* gp = gin + ((long)(dir*T + t)*NB + b)*GE;
#pragma unroll
    for (int nt = 0; nt < 4; ++nt) {
      int nb = n0 + nt*16 + r4;
      f32x4 v = acc[mt][nt];
      float4 o;
      o.x = v[0] + Bias[nb+0];
      o.y = v[1] + Bias[nb+1];
      o.z = v[2] + Bias[nb+2];
      o.w = v[3] + Bias[nb+3];
      *(float4*)(gp + nb) = o;
    }
  }
}

// ---------------------------------------------- encoder recurrent step (t)
__global__ __launch_bounds__(256) void k_enc_step(
    const bf16* __restrict__ fWhh, const bf16* __restrict__ bWhh,
    const float* __restrict__ gin, float* __restrict__ encc,
    const bf16* __restrict__ hin, bf16* __restrict__ hout,
    bf16* __restrict__ encout, int t)
{
  __shared__ float lds[4][16][32];
  int tid = threadIdx.x;
  int w = tid >> 6, lane = tid & 63;
  int dir = blockIdx.x >> 5;
  int j0  = (blockIdx.x & 31) * 16;
  const bf16* Whh   = dir ? bWhh : fWhh;
  const bf16* hbase = hin + dir*(NB*H);
  int col = lane & 15, kq = lane >> 4, r4 = kq*4;
  const bf16* arow = Whh + (long)(w*H + j0 + col)*H + kq*8;
  const bf16* b0 = hbase + col*H + kq*8;
  const bf16* b1 = hbase + (16+col)*H + kq*8;
  f32x4 a0 = {}, a1 = {};
  for (int kk = 0; kk < H/32; ++kk) {
    bf16x8 a = ld8(arow + kk*32);
    a0 = mfma16(a, ld8(b0 + kk*32), a0);
    a1 = mfma16(a, ld8(b1 + kk*32), a1);
  }
#pragma unroll
  for (int r = 0; r < 4; ++r) { lds[w][r4+r][col] = a0[r]; lds[w][r4+r][16+col] = a1[r]; }
  __syncthreads();
  const float* gp = gin + (long)(dir*T + t)*NB*GE;
  for (int idx = tid; idx < 512; idx += 256) {
    int jj = idx >> 5, b = idx & 31;
    int j = j0 + jj;
    const float* g4 = gp + (long)b*GE;
    float ig = lds[0][jj][b] + g4[0*H + j];
    float fg = lds[1][jj][b] + g4[1*H + j];
    float gg = lds[2][jj][b] + g4[2*H + j];
    float og = lds[3][jj][b] + g4[3*H + j];
    float i_ = sigm(ig), f_ = sigm(fg), o_ = sigm(og), g_ = tanhf(gg);
    int ci = (dir*NB + b)*H + j;
    float c2 = f_*encc[ci] + i_*g_;
    encc[ci] = c2;
    float h = o_*tanhf(c2);
    hout[dir*(NB*H) + b*H + j] = (bf16)h;
    encout[((long)b*L + t)*H2 + dir*H + j] = (bf16)h;
  }
}

// -------------------- decoder K1: argmax-reduce + embed + attention + ctx
__global__ __launch_bounds__(256) void k_dec_attn(
    const float* __restrict__ dec_embed, const bf16* __restrict__ wattn,
    const float* __restrict__ attn_b, const bf16* __restrict__ encout,
    const bf16* __restrict__ hin,
    const float* __restrict__ pmax, const float* __restrict__ psum,
    const int* __restrict__ pidx,
    float* __restrict__ logz, bf16* __restrict__ cat2, int t)
{
  __shared__ float red_m[256], red_s[256];
  __shared__ int   red_i[256];
  __shared__ float catF[2*H2];
  __shared__ float aw[64];
  __shared__ int stok;
  int tid = threadIdx.x, b = blockIdx.x;

  if (t > 0) {                       // finish step t-1: logZ + argmax token
    float m = -1e30f, s = 0.f; int id = 0;
    for (int c = tid; c < NCHUNK; c += 256) {
      float cm = pmax[c*32 + b]; int ci = pidx[c*32 + b];
      s += psum[c*32 + b];
      if (cm > m) { m = cm; id = ci; }
      else if (cm == m && ci < id) { id = ci; }
    }
    red_m[tid] = m; red_s[tid] = s; red_i[tid] = id;
    __syncthreads();
    for (int off = 128; off; off >>= 1) {
      if (tid < off) {
        float om = red_m[tid+off]; int oi = red_i[tid+off];
        red_s[tid] += red_s[tid+off];
        if (om > red_m[tid] || (om == red_m[tid] && oi < red_i[tid])) { red_m[tid]=om; red_i[tid]=oi; }
      }
      __syncthreads();
    }
    if (tid == 0) { logz[(t-1)*32 + b] = logf(red_s[0]); stok = red_i[0]; }
  } else {
    if (tid == 0) stok = SOS;
  }
  __syncthreads();
  int tok = stok;

  // phase 1: catF = [e, h] (f32 in LDS); e -> cat2 ws as bf16
  const float* erow = dec_embed + (long)tok*H2;
  bf16* c2row = cat2 + (long)b*(2*H2);
  if (tid < 128) {
    int o = tid*8;
    float4 a = *(const float4*)(erow + o);
    float4 c = *(const float4*)(erow + o + 4);
    catF[o+0]=a.x; catF[o+1]=a.y; catF[o+2]=a.z; catF[o+3]=a.w;
    catF[o+4]=c.x; catF[o+5]=c.y; catF[o+6]=c.z; catF[o+7]=c.w;
    bf16x8 v;
    v[0]=(bf16)a.x; v[1]=(bf16)a.y; v[2]=(bf16)a.z; v[3]=(bf16)a.w;
    v[4]=(bf16)c.x; v[5]=(bf16)c.y; v[6]=(bf16)c.z; v[7]=(bf16)c.w;
    *(bf16x8*)(c2row + o) = v;
  } else {
    int o = (tid - 128)*8;
    bf16x8 hv = ld8(hin + (long)b*H2 + o);
#pragma unroll
    for (int e = 0; e < 8; ++e) catF[H2 + o + e] = (float)hv[e];
  }
  __syncthreads();

  // phase 2: scores[l] = catF . wattn[l] + attn_b[l]   (4 threads per l)
  {
    int l = tid >> 2, q = tid & 3;
    const bf16*  wrow = wattn + (long)l*(2*H2) + q*512;
    const float* crow = catF + q*512;
    float sacc = 0.f;
    for (int k = 0; k < 512; k += 8) {
      bf16x8 wv = ld8(wrow + k);
#pragma unroll
      for (int e = 0; e < 8; ++e) sacc += (float)wv[e] * crow[k+e];
    }
    sacc += __shfl_xor(sacc, 1);
    sacc += __shfl_xor(sacc, 2);
    if (q == 0) aw[l] = sacc + attn_b[l];
  }
  __syncthreads();

  // phase 3: softmax over L=64 (wave 0)
  if (tid < 64) {
    float v = aw[tid];
    float m = v;
#pragma unroll
    for (int off = 1; off < 64; off <<= 1) m = fmaxf(m, __shfl_xor(m, off));
    float p = __expf(v - m);
    float s = p;
#pragma unroll
    for (int off = 1; off < 64; off <<= 1) s += __shfl_xor(s, off);
    aw[tid] = p / s;
  }
  __syncthreads();

  // phase 4: ctx[j] = sum_l aw[l] * enc_outs[b][l][j]  -> cat2[b][H2+j] bf16
  {
    const bf16* eo = encout + (long)b*L*H2;
    int j = tid * 4;
    float4 acc = {0.f, 0.f, 0.f, 0.f};
    for (int l = 0; l < L; ++l) {
      float a = aw[l];
      bf16x4 v = *(const bf16x4*)(eo + (long)l*H2 + j);
      acc.x += a*(float)v[0]; acc.y += a*(float)v[1];
      acc.z += a*(float)v[2]; acc.w += a*(float)v[3];
    }
    bf16x4 o;
    o[0] = (bf16)acc.x; o[1] = (bf16)acc.y; o[2] = (bf16)acc.z; o[3] = (bf16)acc.w;
    *(bf16x4*)(c2row + H2 + j) = o;
  }
}

// -------------------------- decoder K1b: comb = relu(cat2 @ comb_W.T + b)
// 16 blocks x 4 waves; one 16-row tile per wave.
__global__ __launch_bounds__(256) void k_dec_comb(
    const bf16* __restrict__ comb_W, const float* __restrict__ comb_b,
    const bf16* __restrict__ cat2, bf16* __restrict__ comb)
{
  int wid = blockIdx.x * 4 + (threadIdx.x >> 6);  // 0..63
  int lane = threadIdx.x & 63;
  int col = lane & 15, kq = lane >> 4, r4 = kq*4;
  int n0 = wid * 16;
  const bf16* arow = comb_W + (long)(n0 + col)*(2*H2) + kq*8;
  const bf16* b0 = cat2 + (long)col*(2*H2) + kq*8;
  const bf16* b1 = cat2 + (long)(16+col)*(2*H2) + kq*8;
  f32x4 acc0 = {}, acc1 = {};
  for (int kk = 0; kk < 64; ++kk) {
    bf16x8 a = ld8(arow + kk*32);
    acc0 = mfma16(a, ld8(b0 + kk*32), acc0);
    acc1 = mfma16(a, ld8(b1 + kk*32), acc1);
  }
#pragma unroll
  for (int bt = 0; bt < 2; ++bt) {
    int b = bt*16 + col;
    f32x4 v = bt ? acc1 : acc0;
    bf16x4 o;
#pragma unroll
    for (int r = 0; r < 4; ++r) o[r] = (bf16)fmaxf(v[r] + comb_b[n0 + r4 + r], 0.f);
    *(bf16x4*)(comb + (long)b*H2 + n0 + r4) = o;
  }
}

// ---------------- decoder K2: gates = comb@dWih.T + hh + b; LSTM cell
// (hh = dWhh@h precomputed by previous step's k_dec_logits extra blocks)
__global__ __launch_bounds__(256) void k_dec_cell(
    const bf16* __restrict__ dWih, const float* __restrict__ db,
    const bf16* __restrict__ comb, const float* __restrict__ hh,
    float* __restrict__ decc, bf16* __restrict__ hout)
{
  __shared__ float lds[4][16][32];
  int tid = threadIdx.x, w = tid >> 6, lane = tid & 63;
  int col = lane & 15, kq = lane >> 4, r4 = kq*4;
  int j0 = blockIdx.x * 16;
  int n = w*H2 + j0 + col;
  f32x4 a0 = {}, a1 = {};
  const bf16* arow = dWih + (long)n*H2 + kq*8;
  const bf16* b0 = comb + (long)col*H2 + kq*8;
  const bf16* b1 = comb + (long)(16+col)*H2 + kq*8;
  for (int kk = 0; kk < 32; ++kk) {
    bf16x8 a = ld8(arow + kk*32);
    a0 = mfma16(a, ld8(b0 + kk*32), a0);
    a1 = mfma16(a, ld8(b1 + kk*32), a1);
  }
#pragma unroll
  for (int r = 0; r < 4; ++r) {
    float bias = db[w*H2 + j0 + r4 + r];
    lds[w][r4+r][col] = a0[r] + bias;
    lds[w][r4+r][16+col] = a1[r] + bias;
  }
  __syncthreads();
  for (int idx = tid; idx < 512; idx += 256) {
    int jj = idx >> 5, b = idx & 31;
    int j = j0 + jj;
    float i_ = sigm(lds[0][jj][b] + hh[(0*H2 + j)*32 + b]);
    float f_ = sigm(lds[1][jj][b] + hh[(1*H2 + j)*32 + b]);
    float g_ = tanhf(lds[2][jj][b] + hh[(2*H2 + j)*32 + b]);
    float o_ = sigm(lds[3][jj][b] + hh[(3*H2 + j)*32 + b]);
    float c2 = f_*decc[b*H2 + j] + i_*g_;
    decc[b*H2 + j] = c2;
    hout[b*H2 + j] = (bf16)(o_*tanhf(c2));
  }
}

// ------------- decoder K3: logits (f32) -> d_out raw + per-wave partials.
// blocks 0..499: logits (16 rows/wave).  blocks 500..563: hh = dWhh@h(t) for
// next step's cell (rides for free in the same dispatch).
__global__ __launch_bounds__(256) void k_dec_logits(
    const bf16* __restrict__ outW, const float* __restrict__ outb,
    const bf16* __restrict__ dWhh, const bf16* __restrict__ hvec,
    float* __restrict__ out, float* __restrict__ hh,
    float* __restrict__ pmax, float* __restrict__ psum, int* __restrict__ pidx,
    int t)
{
  int w = threadIdx.x >> 6, lane = threadIdx.x & 63;
  int col = lane & 15, kq = lane >> 4, r4 = kq*4;
  const bf16* b0 = hvec + (long)col*H2 + kq*8;
  const bf16* b1 = hvec + (long)(16+col)*H2 + kq*8;

  if (blockIdx.x < 500) {
    int wid = blockIdx.x * 4 + w;      // 0..1999
    int n0 = wid * 16;
    const bf16* arow = outW + (long)(n0 + col)*H2 + kq*8;
    f32x4 acc0 = {}, acc1 = {};
    for (int kk = 0; kk < 32; ++kk) {
      bf16x8 a = ld8(arow + kk*32);
      acc0 = mfma16(a, ld8(b0 + kk*32), acc0);
      acc1 = mfma16(a, ld8(b1 + kk*32), acc1);
    }
    float m[2] = {-1e30f, -1e30f};
    float s[2] = {0.f, 0.f};
    int  id[2] = {0, 0};
#pragma unroll
    for (int bt = 0; bt < 2; ++bt) {
      int b = bt*16 + col;
      float* orow = out + ((long)b*T + t)*V + n0 + r4;
      f32x4 v = bt ? acc1 : acc0;
      float4 o;
      float xs[4];
#pragma unroll
      for (int r = 0; r < 4; ++r) {
        float xv = v[r] + outb[n0 + r4 + r];
        xs[r] = xv;
        s[bt] += __expf(xv);
        if (xv > m[bt]) { m[bt] = xv; id[bt] = n0 + r4 + r; }
      }
      o.x = xs[0]; o.y = xs[1]; o.z = xs[2]; o.w = xs[3];
      *(float4*)orow = o;
    }
#pragma unroll
    for (int off = 16; off <= 32; off <<= 1) {
#pragma unroll
      for (int bt = 0; bt < 2; ++bt) {
        float om = __shfl_xor(m[bt], off);
        float os = __shfl_xor(s[bt], off);
        int   oi = __shfl_xor(id[bt], off);
        s[bt] += os;
        if (om > m[bt] || (om == m[bt] && oi < id[bt])) { m[bt] = om; id[bt] = oi; }
      }
    }
    if (lane < 16) {
#pragma unroll
      for (int bt = 0; bt < 2; ++bt) {
        int b = bt*16 + lane;
        pmax[wid*32 + b] = m[bt];
        psum[wid*32 + b] = s[bt];
        pidx[wid*32 + b] = id[bt];
      }
    }
  } else {
    int wid = (blockIdx.x - 500) * 4 + w;  // 0..255
    int n0 = wid * 16;                      // rows of dWhh (4*H2 = 4096)
    const bf16* arow = dWhh + (long)(n0 + col)*H2 + kq*8;
    f32x4 acc0 = {}, acc1 = {};
    for (int kk = 0; kk < 32; ++kk) {
      bf16x8 a = ld8(arow + kk*32);
      acc0 = mfma16(a, ld8(b0 + kk*32), acc0);
      acc1 = mfma16(a, ld8(b1 + kk*32), acc1);
    }
#pragma unroll
    for (int bt = 0; bt < 2; ++bt) {
      int b = bt*16 + col;
      f32x4 v = bt ? acc1 : acc0;
#pragma unroll
      for (int r = 0; r < 4; ++r) hh[(n0 + r4 + r)*32 + b] = v[r];
    }
  }
}

// ------------------------------------------------ logZ for the last step
__global__ __launch_bounds__(256) void k_reduce_last(const float* __restrict__ psum,
                                                     float* __restrict__ logz)
{
  __shared__ float red_s[256];
  int tid = threadIdx.x, b = blockIdx.x;
  float s = 0.f;
  for (int c = tid; c < NCHUNK; c += 256) s += psum[c*32 + b];
  red_s[tid] = s;
  __syncthreads();
  for (int off = 128; off; off >>= 1) { if (tid < off) red_s[tid] += red_s[tid+off]; __syncthreads(); }
  if (tid == 0) logz[63*32 + b] = logf(red_s[0]);
}

// ------------------------- final: out[b][t][v] = raw_logit - logZ[t][b]
__global__ __launch_bounds__(256) void k_fixup(float* __restrict__ out,
                                               const float* __restrict__ logz)
{
  long i = (long)blockIdx.x * 256 + threadIdx.x;
  long stride = (long)gridDim.x * 256;
  long total = (long)NB * T * V / 4;
  for (long g = i; g < total; g += stride) {
    long flat = g * 4;
    long bt = flat / V;                 // = b*T + t
    int tt = (int)(bt & 63), b = (int)(bt >> 6);
    float lz = logz[tt*32 + b];
    float4 v = *(const float4*)(out + flat);
    v.x -= lz; v.y -= lz; v.z -= lz; v.w -= lz;
    *(float4*)(out + flat) = v;
  }
}

extern "C" void kernel_launch(void* const* d_in, const int* in_sizes, int n_in,
                              void* d_out, int out_size, void* d_ws, size_t ws_size,
                              hipStream_t stream)
{
  const int*   x         = (const int*)  d_in[0];
  const float* enc_embed = (const float*)d_in[1];
  const float* ef_Wih    = (const float*)d_in[2];
  const float* ef_Whh    = (const float*)d_in[3];
  const float* ef_b      = (const float*)d_in[4];
  const float* eb_Wih    = (const float*)d_in[5];
  const float* eb_Whh    = (const float*)d_in[6];
  const float* eb_b      = (const float*)d_in[7];
  const float* dec_embed = (const float*)d_in[8];
  const float* attn_W    = (const float*)d_in[9];
  const float* attn_b    = (const float*)d_in[10];
  const float* comb_W    = (const float*)d_in[11];
  const float* comb_b    = (const float*)d_in[12];
  const float* d_Wih     = (const float*)d_in[13];
  const float* d_Whh     = (const float*)d_in[14];
  const float* d_b       = (const float*)d_in[15];
  const float* out_W     = (const float*)d_in[16];
  const float* out_b     = (const float*)d_in[17];
  float* out = (float*)d_out;
  char* ws = (char*)d_ws;

  float* gin    = (float*)(ws + OFF_GIN);
  bf16*  encout = (bf16*) (ws + OFF_ENCOUT);
  float* encc   = (float*)(ws + OFF_ENCC);
  bf16*  ench   = (bf16*) (ws + OFF_ENCH);
  float* decc   = (float*)(ws + OFF_DECC);
  bf16*  dech   = (bf16*) (ws + OFF_DECH);
  bf16*  cat2   = (bf16*) (ws + OFF_CAT2);
  bf16*  comb   = (bf16*) (ws + OFF_COMB);
  float* hh     = (float*)(ws + OFF_HH);
  float* pmax   = (float*)(ws + OFF_PMAX);
  float* psum   = (float*)(ws + OFF_PSUM);
  int*   pidx   = (int*)  (ws + OFF_PIDX);
  float* logz   = (float*)(ws + OFF_LOGZ);
  bf16*  wefih  = (bf16*) (ws + OFF_WEFIH);
  bf16*  wefhh  = (bf16*) (ws + OFF_WEFHH);
  bf16*  webih  = (bf16*) (ws + OFF_WEBIH);
  bf16*  webhh  = (bf16*) (ws + OFF_WEBHH);
  bf16*  wcomb  = (bf16*) (ws + OFF_WCOMB);
  bf16*  wdih   = (bf16*) (ws + OFF_WDIH);
  bf16*  wdhh   = (bf16*) (ws + OFF_WDHH);
  bf16*  wout   = (bf16*) (ws + OFF_WOUT);
  bf16*  wattn  = (bf16*) (ws + OFF_WATTN);
  bf16*  emb2   = (bf16*) (ws + OFF_EMB2);

  ConvJobs J;
  J.src[0]=ef_Wih; J.dst[0]=wefih; J.n8[0]=(long)GE*E/8;
  J.src[1]=ef_Whh; J.dst[1]=wefhh; J.n8[1]=(long)GE*H/8;
  J.src[2]=eb_Wih; J.dst[2]=webih; J.n8[2]=(long)GE*E/8;
  J.src[3]=eb_Whh; J.dst[3]=webhh; J.n8[3]=(long)GE*H/8;
  J.src[4]=comb_W; J.dst[4]=wcomb; J.n8[4]=(long)H2*2*H2/8;
  J.src[5]=d_Wih;  J.dst[5]=wdih;  J.n8[5]=(long)4*H2*H2/8;
  J.src[6]=d_Whh;  J.dst[6]=wdhh;  J.n8[6]=(long)4*H2*H2/8;
  J.src[7]=out_W;  J.dst[7]=wout;  J.n8[7]=(long)V*H2/8;
  J.src[8]=attn_W; J.dst[8]=wattn; J.n8[8]=(long)L*2*H2/8;
  hipLaunchKernelGGL(k_convert_all, dim3(2048), dim3(256), 0, stream, J);
  hipLaunchKernelGGL(k_gather_emb, dim3(512), dim3(256), 0, stream, x, enc_embed, emb2);
  hipLaunchKernelGGL(k_init, dim3(512), dim3(256), 0, stream, encc, ench, decc, dech, hh);

  hipLaunchKernelGGL(k_enc_ingemm, dim3(1024), dim3(256), 0, stream,
                     emb2, wefih, ef_b, webih, eb_b, gin);
  for (int t = 0; t < T; ++t) {
    const bf16* hi = ench + (t & 1) * (2*NB*H);
    bf16*       ho = ench + ((t & 1) ^ 1) * (2*NB*H);
    hipLaunchKernelGGL(k_enc_step, dim3(64), dim3(256), 0, stream,
                       wefhh, webhh, gin, encc, hi, ho, encout, t);
  }
  for (int t = 0; t < T; ++t) {
    const bf16* hi = dech + (t & 1) * (NB*H2);
    bf16*       ho = dech + ((t & 1) ^ 1) * (NB*H2);
    hipLaunchKernelGGL(k_dec_attn, dim3(32), dim3(256), 0, stream,
                       dec_embed, wattn, attn_b, encout, hi, pmax, psum, pidx, logz, cat2, t);
    hipLaunchKernelGGL(k_dec_comb, dim3(16), dim3(256), 0, stream, wcomb, comb_b, cat2, comb);
    hipLaunchKernelGGL(k_dec_cell, dim3(64), dim3(256), 0, stream,
                       wdih, d_b, comb, hh, decc, ho);
    hipLaunchKernelGGL(k_dec_logits, dim3(564), dim3(256), 0, stream,
                       wout, out_b, wdhh, ho, out, hh, pmax, psum, pidx, t);
  }
  hipLaunchKernelGGL(k_reduce_last, dim3(32), dim3(256), 0, stream, psum, logz);
  hipLaunchKernelGGL(k_fixup, dim3(2048), dim3(256), 0, stream, out, logz);
}